// Round 17
// baseline (118.009 us; speedup 1.0000x reference)
//
#include <hip/hip_runtime.h>

#define B_N 256
#define IC_N 1152
#define J_N 10
#define D_N 16

typedef __attribute__((ext_vector_type(8))) short short8;
typedef __attribute__((ext_vector_type(4))) float floatx4;

union u4s8 { uint4 u; short8 s; };

__device__ __forceinline__ float bf_lo(unsigned int u){
  union { unsigned int i; float f; } c; c.i = u << 16; return c.f;
}
__device__ __forceinline__ float bf_hi(unsigned int u){
  union { unsigned int i; float f; } c; c.i = u & 0xffff0000u; return c.f;
}
__device__ __forceinline__ unsigned int rne16(float f){
  union { float ff; unsigned int i; } c; c.ff = f;
  return (c.i + 0x7FFFu + ((c.i >> 16) & 1u)) >> 16;
}
__device__ __forceinline__ unsigned int pack_rne(float lo, float hi){
  return rne16(lo) | (rne16(hi) << 16);
}
__device__ __forceinline__ unsigned int pack_trunc(float lo, float hi){
  union { float f; unsigned int u; } a, b; a.f = lo; b.f = hi;
  return __builtin_amdgcn_perm(b.u, a.u, 0x07060302u);
}

// prep (R14/R16-proven): W once -> wsf + wcc2 frags; zero s0/s1/s2.
__global__ __launch_bounds__(256) void caps_prep(
    const float* __restrict__ W, uint4* __restrict__ wsf,
    uint4* __restrict__ wcc2, float* __restrict__ s_zero)
{
  const int tid = threadIdx.x;
  const int t0 = blockIdx.x * 256 + tid;
  if (t0 < 3 * B_N * J_N * D_N) s_zero[t0] = 0.f;   // s0,s1,s2 (atomic accum)
  __shared__ unsigned int lw[1024];
  const int j = blockIdx.x / 72, itile = blockIdx.x % 72;
  const float4* Wt = (const float4*)(W + ((size_t)(j * IC_N + itile * 16) << 7));
  #pragma unroll
  for (int h = 0; h < 2; ++h) {
    const float4 f = Wt[h * 256 + tid];
    lw[(h * 256 + tid) * 2]     = pack_rne(f.x, f.y);
    lw[(h * 256 + tid) * 2 + 1] = pack_rne(f.z, f.w);
  }
  __syncthreads();
  {  // wsf emit (layout verified R5..R16)
    const int ktl = tid >> 6, ln = tid & 63;
    const int base = (ktl * 4 + (ln >> 4)) * 64 + (ln & 15) * 4;
    uint4 q;
    q.x = lw[base]; q.y = lw[base + 1]; q.z = lw[base + 2]; q.w = lw[base + 3];
    wsf[((size_t)j * 288 + itile * 4 + ktl) * 64 + ln] = q;
  }
  {  // wcc2 emit (layout verified R6..R16)
    const int e = tid >> 5, lane2 = tid & 31;
    const int il = lane2 & 15, dbase = (lane2 >> 4) * 8;
    unsigned short h[8];
    #pragma unroll
    for (int k = 0; k < 8; ++k) {
      const unsigned int u = lw[il * 64 + (dbase + k) * 4 + (e >> 1)];
      h[k] = (e & 1) ? (unsigned short)(u >> 16) : (unsigned short)(u & 0xffffu);
    }
    uint4 q;
    q.x = h[0] | ((unsigned int)h[1] << 16);
    q.y = h[2] | ((unsigned int)h[3] << 16);
    q.z = h[4] | ((unsigned int)h[5] << 16);
    q.w = h[6] | ((unsigned int)h[7] << 16);
    wcc2[(((size_t)j * 8 + e) * 72 + itile) * 32 + lane2] = q;
  }
}

// Pass (R16-proven internals; squash of previous rounds FUSED at block start).
// grid (16 btiles, 72 chunks), 320 thr = 5 waves, wave handles j=2w,2w+1.
// vsum for this block's 16 b is recomputed redundantly (10 KB L2-warm reads,
// shared by the 72 blocks of a btile) -> no squash dispatches, no vsbf buffer.
// s accumulated via fp32 agent atomics (R2-R4-proven; 72 adds/address).
__global__ __launch_bounds__(320, 5) void caps_pass(
    const float* __restrict__ x,
    const uint4* __restrict__ wsf, const uint4* __restrict__ wcc2,
    const float* __restrict__ s0, const float* __restrict__ s1,
    float* __restrict__ s_w, const int round)
{
  __shared__ float ccl[10 * 16 * 17];      // [j][i16][b pad17], 10.6 KB
  __shared__ unsigned int xt[16 * 17 * 4]; // [i][b pad17] uint4,  4.3 KB
  __shared__ unsigned int vsh[160 * 8];    // vsum bf16 frags [bl*10+j][8], 5 KB

  const int tid  = threadIdx.x;
  const int wave = tid >> 6;               // 0..4
  const int lane = tid & 63;
  const int quad = lane >> 4;
  const int col  = lane & 15;
  const int b0   = blockIdx.x << 4;        // 16 b
  const int i0   = blockIdx.y << 4;        // 16 i

  // ---- stage x tile (16 b x 16 i) ----
  for (int p = tid; p < 512; p += 320) {
    const int b = p >> 5, u = p & 31, i = u >> 1, half = u & 1;
    const float4 v = ((const float4*)(x + ((size_t)((b0 + b) * IC_N + i0 + i) << 3)))[half];
    const int idx = ((i * 17 + b) << 2) + (half << 1);
    xt[idx]     = pack_rne(v.x, v.y);
    xt[idx + 1] = pack_rne(v.z, v.w);
  }
  // ---- fused squash: vsum = sum_{r'<round} squash(s_{r'}) for our 16 b ----
  if (round > 0 && tid < 160) {
    const int j = tid >> 4, bl = tid & 15;   // 10 x 16
    float vacc[16];
    #pragma unroll
    for (int d = 0; d < 16; ++d) vacc[d] = 0.f;
    for (int rr = 0; rr < round; ++rr) {
      const float* sp = (rr == 0 ? s0 : s1) + ((size_t)(b0 + bl) * 160 + j * 16);
      float sv[16];
      float sq = 0.f;
      #pragma unroll
      for (int d = 0; d < 16; ++d) { sv[d] = sp[d]; sq += sv[d] * sv[d]; }
      const float coef = (sq / (1.f + sq)) * rsqrtf(sq + 1e-7f);
      #pragma unroll
      for (int d = 0; d < 16; ++d) vacc[d] += coef * sv[d];
    }
    #pragma unroll
    for (int k = 0; k < 8; ++k)
      vsh[(bl * 10 + j) * 8 + k] = pack_rne(vacc[2 * k], vacc[2 * k + 1]);
  }
  __syncthreads();
  const uint4* xtq = (const uint4*)xt;

  if (round > 0) {
    uint4 xr[4];                           // x[b=quad*4+r][i=col] (both j's)
    #pragma unroll
    for (int r = 0; r < 4; ++r)
      xr[r] = xtq[col * 17 + quad * 4 + r];
    #pragma unroll
    for (int jj = 0; jj < 2; ++jj) {
      const int j = wave * 2 + jj;
      short8 av = {0,0,0,0,0,0,0,0};       // vsum[b=col][d]; quads 2,3 K-pad
      if (quad < 2)
        av = *(const short8*)&vsh[(col * 10 + j) * 8 + quad * 4];
      uint4 bvq[8];
      #pragma unroll
      for (int e = 0; e < 8; ++e) {
        uint4 q = {0u, 0u, 0u, 0u};
        if (lane < 32)
          q = wcc2[(((size_t)j * 8 + e) * 72 + blockIdx.y) * 32 + lane];
        bvq[e] = q;
      }
      floatx4 cc4 = {0.f, 0.f, 0.f, 0.f};
      #pragma unroll
      for (int e = 0; e < 8; ++e) {
        u4s8 bv; bv.u = bvq[e];
        floatx4 tf = {0.f, 0.f, 0.f, 0.f};
        tf = __builtin_amdgcn_mfma_f32_16x16x32_bf16(av, bv.s, tf, 0, 0, 0);
        #pragma unroll
        for (int r = 0; r < 4; ++r) {
          const unsigned int u = ((const unsigned int*)&xr[r])[e >> 1];
          const float xe = (e & 1) ? bf_hi(u) : bf_lo(u);
          cc4[r] += tf[r] * xe;
        }
      }
      #pragma unroll
      for (int r = 0; r < 4; ++r)
        ccl[(j * 16 + col) * 17 + quad * 4 + r] = cc4[r];
    }
    __syncthreads();
    if (tid < 256) {                       // softmax over j per (i,b), in place
      const int i = tid >> 4, b = tid & 15;
      float cc[10];
      #pragma unroll
      for (int j = 0; j < 10; ++j) cc[j] = ccl[(j * 16 + i) * 17 + b];
      float m = cc[0];
      #pragma unroll
      for (int j = 1; j < 10; ++j) m = fmaxf(m, cc[j]);
      float den = 0.f;
      #pragma unroll
      for (int j = 0; j < 10; ++j) { cc[j] = __expf(cc[j] - m); den += cc[j]; }
      const float rd = __builtin_amdgcn_rcpf(den);
      #pragma unroll
      for (int j = 0; j < 10; ++j) ccl[(j * 16 + i) * 17 + b] = cc[j] * rd;
    }
    __syncthreads();
  }

  // ---- phase B: s[b,d] += (c*x) @ Ws, K=128; atomic accumulate into s_w ----
  #pragma unroll
  for (int jj = 0; jj < 2; ++jj) {
    const int j = wave * 2 + jj;
    floatx4 acc = {0.f, 0.f, 0.f, 0.f};
    #pragma unroll
    for (int kt = 0; kt < 4; ++kt) {
      const int il = kt * 4 + quad;
      const uint4 xq = xtq[il * 17 + col];
      const uint4 wf = wsf[((size_t)j * 288 + (blockIdx.y << 2) + kt) * 64 + lane];
      const float c = (round > 0) ? ccl[(j * 16 + il) * 17 + col] : 0.1f;
      short8 af;
      unsigned int* aq = (unsigned int*)&af;
      aq[0] = pack_trunc(bf_lo(xq.x) * c, bf_hi(xq.x) * c);
      aq[1] = pack_trunc(bf_lo(xq.y) * c, bf_hi(xq.y) * c);
      aq[2] = pack_trunc(bf_lo(xq.z) * c, bf_hi(xq.z) * c);
      aq[3] = pack_trunc(bf_lo(xq.w) * c, bf_hi(xq.w) * c);
      u4s8 bw; bw.u = wf;
      acc = __builtin_amdgcn_mfma_f32_16x16x32_bf16(af, bw.s, acc, 0, 0, 0);
    }
    #pragma unroll
    for (int r = 0; r < 4; ++r)
      __hip_atomic_fetch_add(&s_w[(size_t)(b0 + quad * 4 + r) * 160 + j * 16 + col],
                             acc[r], __ATOMIC_RELAXED, __HIP_MEMORY_SCOPE_AGENT);
  }
}

// final output squash: out[b,j,d] = squash(s2)[b,j,d]. 160 blocks x 256.
__global__ __launch_bounds__(256) void caps_outsq(
    const float* __restrict__ s2, float* __restrict__ out)
{
  const int t = blockIdx.x * 256 + threadIdx.x;   // 40960 = flat [b][j][d]
  const float s = s2[t];
  float sq = s * s;
  sq += __shfl_xor(sq, 1, 16);
  sq += __shfl_xor(sq, 2, 16);
  sq += __shfl_xor(sq, 4, 16);
  sq += __shfl_xor(sq, 8, 16);
  const float coef = (sq / (1.f + sq)) * rsqrtf(sq + 1e-7f);
  out[t] = coef * s;
}

extern "C" void kernel_launch(void* const* d_in, const int* in_sizes, int n_in,
                              void* d_out, int out_size, void* d_ws, size_t ws_size,
                              hipStream_t stream)
{
  const float* x_p = (const float*)d_in[0];   // [256][1152][8] fp32
  const float* W_p = (const float*)d_in[1];   // [10][1152][16][8] fp32

  // ws: wsf 2.95M | wcc2 2.95M | s0,s1,s2 3x160K (~6.4 MB total)
  uint4* wsf  = (uint4*)d_ws;
  uint4* wcc2 = wsf + 184320;
  float* s0   = (float*)(wcc2 + 184320);      // 40960 f, [b][j][d]
  float* s1   = s0 + 40960;
  float* s2   = s1 + 40960;
  float* out_p = (float*)d_out;

  caps_prep<<<dim3(720), dim3(256), 0, stream>>>(W_p, wsf, wcc2, s0);
  caps_pass<<<dim3(16, 72), dim3(320), 0, stream>>>(x_p, wsf, wcc2, s0, s1, s0, 0);
  caps_pass<<<dim3(16, 72), dim3(320), 0, stream>>>(x_p, wsf, wcc2, s0, s1, s1, 1);
  caps_pass<<<dim3(16, 72), dim3(320), 0, stream>>>(x_p, wsf, wcc2, s0, s1, s2, 2);
  caps_outsq<<<dim3(160), dim3(256), 0, stream>>>(s2, out_p);
}